// Round 4
// baseline (17.970 us; speedup 1.0000x reference)
//
#include <hip/hip_runtime.h>
#include <math.h>

// Problem constants (fixed by setup_inputs): B=8, E=8, F=16, T=2048, k=32
constexpr int Bd = 8;
constexpr int Ed = 8;
constexpr int Fd = 16;
constexpr int Td = 2048;
constexpr int K  = 32;

constexpr int TG   = 16;          // t-groups per block (lanes per f)
constexpr int TPT  = 4;           // t's per thread
constexpr int TT   = TG * TPT;    // 64 t covered per block
constexpr int HALO = K - 1;       // 31
constexpr int WIN  = TT + HALO;   // 95 staged |exo| values per f
constexpr int STRIDE = 100;       // LDS row stride (mult of 4 for float4 alignment)

typedef float f32x4 __attribute__((ext_vector_type(4)));

// Algebraic simplification of the reference:
//   product = q*kv; |product| = |q|*|kv|; sign(product)*kv = sign(q)*|kv|
//   out[b][e][f][t] = sign(q) * sum_j softmax_j(|q|*a_j) * a_j,  a_j = |exo| window
//   out[b][e][16][t] = endo[b][e][t]
// Softmax shift uses the UNION max M over va[0..34] (valid for any shift;
// worst-case exp2 arg ~ -55, far above denormal range).
__global__ __launch_bounds__(256, 4) void tca_kernel(
    const float* __restrict__ endo,
    const float* __restrict__ exo,
    const float* __restrict__ w_expand,
    const float* __restrict__ b_expand,
    float* __restrict__ out)
{
    __shared__ float a_s[Fd * STRIDE];

    const int tid = threadIdx.x;
    const int b   = blockIdx.z;
    const int e   = blockIdx.y;
    const int t0  = blockIdx.x * TT;

    const int f  = tid >> 4;   // 0..15
    const int tg = tid & 15;   // 0..15
    const int t  = t0 + tg * TPT;

    // independent loads issued before the barrier
    const float4 qv = *reinterpret_cast<const float4*>(&endo[(b * Ed + e) * Td + t]);
    const float wf  = w_expand[e * Fd + f];
    const float bf  = b_expand[e * Fd + f];

    // ---- stage |exo[b, :, t0-31 .. t0+63]| into LDS (zeros for t<0) ----
    {
        const float* src = &exo[(b * Fd + f) * Td + t0 - HALO];
        #pragma unroll
        for (int k = 0; k < 6; ++k) {
            const int i = tg + k * 16;
            if (i < WIN) {
                const int tt = t0 - HALO + i;
                const float v = (tt >= 0) ? src[i] : 0.f;
                a_s[f * STRIDE + i] = fabsf(v);
            }
        }
    }
    __syncthreads();

    // passthrough channel (f == 16 slot)
    if (f == 0) {
        *reinterpret_cast<float4*>(
            &out[(((b * Ed + e) * (Fd + 1)) + Fd) * Td + t]) = qv;
    }

    // ---- union window va[0..34] via 9 aligned float4 LDS reads ----
    float va[36];
    {
        const f32x4* base = reinterpret_cast<const f32x4*>(&a_s[f * STRIDE + tg * TPT]);
        #pragma unroll
        for (int k4 = 0; k4 < 9; ++k4) {
            const f32x4 v4 = base[k4];
            va[4 * k4 + 0] = v4.x;
            va[4 * k4 + 1] = v4.y;
            va[4 * k4 + 2] = v4.z;
            va[4 * k4 + 3] = v4.w;
        }
    }

    // ---- union max over va[0..34], 5 strided partials (independent chains) ----
    float x0 = va[0], x1 = va[1], x2 = va[2], x3 = va[3], x4 = va[4];
    #pragma unroll
    for (int j = 5; j < 35; j += 5) {
        x0 = fmaxf(x0, va[j]);
        x1 = fmaxf(x1, va[j + 1]);
        x2 = fmaxf(x2, va[j + 2]);
        x3 = fmaxf(x3, va[j + 3]);
        x4 = fmaxf(x4, va[j + 4]);
    }
    const float M = fmaxf(fmaxf(x0, x1), fmaxf(x2, fmaxf(x3, x4)));

    constexpr float LOG2E = 1.44269504088896340736f;
    const float qa[4] = {qv.x, qv.y, qv.z, qv.w};

    // per-p constants (constant-indexed arrays, fully unrolled -> registers)
    float c1[4], c0[4], sgn[4];
    float den0[4], den1[4], num0[4], num1[4];
    #pragma unroll
    for (int p = 0; p < 4; ++p) {
        const float q  = fmaf(qa[p], wf, bf);
        const float aq = fabsf(q);
        c1[p] = aq * LOG2E;            // exp(aq*(a-M)) == exp2(a*c1 + c0)
        c0[p] = -M * c1[p];
        sgn[p] = (q > 0.f) ? 1.f : ((q < 0.f) ? -1.f : 0.f);
        den0[p] = den1[p] = num0[p] = num1[p] = 0.f;
    }

    // ---- core: 4 p-streams x 2 j-phases interleaved = 16 indep chains ----
    #pragma unroll
    for (int j = 0; j < K; j += 2) {
        #pragma unroll
        for (int p = 0; p < 4; ++p) {
            const float a0 = va[p + j];
            const float a1 = va[p + j + 1];
            const float e0 = __builtin_amdgcn_exp2f(fmaf(a0, c1[p], c0[p]));
            const float e1 = __builtin_amdgcn_exp2f(fmaf(a1, c1[p], c0[p]));
            den0[p] += e0;
            num0[p] = fmaf(e0, a0, num0[p]);
            den1[p] += e1;
            num1[p] = fmaf(e1, a1, num1[p]);
        }
    }

    float res[4];
    #pragma unroll
    for (int p = 0; p < 4; ++p) {
        const float den = den0[p] + den1[p];
        const float num = num0[p] + num1[p];
        res[p] = sgn[p] * num * __builtin_amdgcn_rcpf(den);
    }

    const float4 r = make_float4(res[0], res[1], res[2], res[3]);
    *reinterpret_cast<float4*>(
        &out[(((b * Ed + e) * (Fd + 1)) + f) * Td + t]) = r;
}

extern "C" void kernel_launch(void* const* d_in, const int* in_sizes, int n_in,
                              void* d_out, int out_size, void* d_ws, size_t ws_size,
                              hipStream_t stream) {
    const float* endo = (const float*)d_in[0];
    const float* exo  = (const float*)d_in[1];
    const float* w    = (const float*)d_in[2];
    const float* bb   = (const float*)d_in[3];
    float* out = (float*)d_out;

    dim3 grid(Td / TT, Ed, Bd);   // (32, 8, 8) = 2048 blocks
    tca_kernel<<<grid, 256, 0, stream>>>(endo, exo, w, bb, out);
}